// Round 1
// baseline (665.644 us; speedup 1.0000x reference)
//
#include <hip/hip_runtime.h>

#define NB 64
#define NC 321
#define ND 512
#define NP 720

#define BN 128
#define BK 64
#define NPT 6   // ceil(720/128) tiles over padded 768

typedef __bf16 bf16x8 __attribute__((ext_vector_type(8)));
typedef float f32x4 __attribute__((ext_vector_type(4)));
typedef unsigned short u16x8 __attribute__((ext_vector_type(8)));
typedef unsigned short u16x4 __attribute__((ext_vector_type(4)));

__device__ __forceinline__ unsigned short f2bf(float f) {
    unsigned int u = __builtin_bit_cast(unsigned int, f);
    return (unsigned short)((u + 0x7FFFu + ((u >> 16) & 1u)) >> 16);
}

// out[m, c, p] = sum_d x[m, c, d] * W[c, d, p] + bias[c, p]
// One block per (channel, p-tile of 128). M=64 (whole batch), BK=64.
// LDS: As[64][64] bf16 (k-contiguous), Bs[128][64] bf16 = W-tile TRANSPOSED
// (n-major, k-contiguous) so MFMA A/B frags are single ds_read_b128.
// XOR swizzle on 16B granules (g ^= row&7) with pitch 128B:
//   - transposed b64 scatter writes of W -> 4-way (= 512B/cycle-phase optimal)
//   - b128 frag reads -> 2-way (free per m136)
__global__ __launch_bounds__(256) void GenLayer_57191784514055_kernel(
    const float* __restrict__ x, const float* __restrict__ W,
    const float* __restrict__ bias, float* __restrict__ out)
{
    const int pt = blockIdx.x;   // 0..5
    const int c  = blockIdx.y;   // 0..320
    const int p0 = pt * BN;

    const int tid  = threadIdx.x;
    const int lane = tid & 63;
    const int wid  = tid >> 6;
    const int lr   = lane & 15;
    const int qd   = lane >> 4;

    __shared__ __align__(16) unsigned short lds[(64 + BN) * BK]; // A:[0,4096) B:[4096,12288)

    // --- A staging: 4 tasks/thread, each one float4 (4 k) of batch-row m ---
    int a_lidx[4];
    const float* a_gp[4];
#pragma unroll
    for (int i = 0; i < 4; ++i) {
        int task = tid + i * 256;
        int m  = task >> 4;          // 0..63
        int kk = (task & 15) << 2;   // 0..60
        a_lidx[i] = m * BK + ((((kk >> 3) ^ (m & 7)) << 3) | (kk & 7));
        a_gp[i]   = x + (size_t)m * (NC * ND) + (size_t)c * ND + kk;
    }

    // --- B staging: 2 tasks/thread, each a 4(d) x 4(p) transpose micro-tile ---
    // task bits chosen so a wave's lanes cover 8 consecutive p-quads (128B
    // coalesced global segments) x 8 d-quads (spreads LDS write banks).
    int b_pl[2], b_dl[2];
    const float* b_gp[2];
    bool b_ok[2];
#pragma unroll
    for (int i = 0; i < 2; ++i) {
        int T  = tid + i * 256;
        int pq = (T & 7) | (((T >> 6) & 1) << 3) | (((T >> 8) & 1) << 4); // 0..31
        int dq = ((T >> 3) & 7) | (((T >> 7) & 1) << 3);                  // 0..15
        b_pl[i] = pq << 2;
        b_dl[i] = dq << 2;
        int pg = p0 + b_pl[i];
        b_ok[i] = (pg < NP);
        b_gp[i] = W + (size_t)c * (ND * NP) + (size_t)b_dl[i] * NP + pg;
    }

    const int mbase = (wid & 1) << 5;   // 0 or 32
    const int nbase = (wid >> 1) << 6;  // 0 or 64

    f32x4 acc[2][4];
#pragma unroll
    for (int ms = 0; ms < 2; ++ms)
#pragma unroll
        for (int ns = 0; ns < 4; ++ns)
            acc[ms][ns] = (f32x4){0.f, 0.f, 0.f, 0.f};

    for (int kt = 0; kt < ND / BK; ++kt) {
        if (kt) __syncthreads();

        // global loads first so they can overlap
        f32x4 av[4];
#pragma unroll
        for (int i = 0; i < 4; ++i)
            av[i] = *(const f32x4*)(a_gp[i] + kt * BK);

        f32x4 bv[2][4];
#pragma unroll
        for (int i = 0; i < 2; ++i) {
#pragma unroll
            for (int r = 0; r < 4; ++r) {
                if (b_ok[i])
                    bv[i][r] = *(const f32x4*)(b_gp[i] + (size_t)(kt * BK + r) * NP);
                else
                    bv[i][r] = (f32x4){0.f, 0.f, 0.f, 0.f};
            }
        }

        // A: k-contiguous b64 writes (conflict-optimal)
#pragma unroll
        for (int i = 0; i < 4; ++i) {
            u16x4 v = { f2bf(av[i][0]), f2bf(av[i][1]), f2bf(av[i][2]), f2bf(av[i][3]) };
            *(u16x4*)(&lds[a_lidx[i]]) = v;
        }
        // B: transposed b64 writes, 4 bf16 along d per write
#pragma unroll
        for (int i = 0; i < 2; ++i) {
#pragma unroll
            for (int j = 0; j < 4; ++j) {
                int p = b_pl[i] + j;
                int d = b_dl[i];
                u16x4 v = { f2bf(bv[i][0][j]), f2bf(bv[i][1][j]),
                            f2bf(bv[i][2][j]), f2bf(bv[i][3][j]) };
                int idx = 64 * BK + p * BK + ((((d >> 3) ^ (p & 7)) << 3) | (d & 7));
                *(u16x4*)(&lds[idx]) = v;
            }
        }

        __syncthreads();

#pragma unroll
        for (int ks = 0; ks < 2; ++ks) {
            const int gk = ks * 4 + qd;   // 16B granule index within BK
            bf16x8 af[2], bfr[4];
#pragma unroll
            for (int ms = 0; ms < 2; ++ms) {
                int row = mbase + ms * 16 + lr;
                af[ms] = __builtin_bit_cast(bf16x8,
                    *(const u16x8*)(&lds[row * BK + ((gk ^ (row & 7)) << 3)]));
            }
#pragma unroll
            for (int ns = 0; ns < 4; ++ns) {
                int n = nbase + ns * 16 + lr;
                bfr[ns] = __builtin_bit_cast(bf16x8,
                    *(const u16x8*)(&lds[64 * BK + n * BK + ((gk ^ (n & 7)) << 3)]));
            }
#pragma unroll
            for (int ms = 0; ms < 2; ++ms)
#pragma unroll
                for (int ns = 0; ns < 4; ++ns)
                    acc[ms][ns] = __builtin_amdgcn_mfma_f32_16x16x32_bf16(
                        af[ms], bfr[ns], acc[ms][ns], 0, 0, 0);
        }
    }

    // epilogue: C/D layout col = lane&15 (p), row = (lane>>4)*4 + reg (m)
#pragma unroll
    for (int ns = 0; ns < 4; ++ns) {
        int p = p0 + nbase + ns * 16 + lr;
        if (p < NP) {
            float bb = bias[c * NP + p];
#pragma unroll
            for (int ms = 0; ms < 2; ++ms) {
                int row0 = mbase + ms * 16 + qd * 4;
                float* op = out + (size_t)row0 * (NC * NP) + (size_t)c * NP + p;
#pragma unroll
                for (int r = 0; r < 4; ++r)
                    op[(size_t)r * (NC * NP)] = acc[ms][ns][r] + bb;
            }
        }
    }
}

extern "C" void kernel_launch(void* const* d_in, const int* in_sizes, int n_in,
                              void* d_out, int out_size, void* d_ws, size_t ws_size,
                              hipStream_t stream) {
    const float* x  = (const float*)d_in[0];
    const float* W  = (const float*)d_in[1];
    const float* b  = (const float*)d_in[2];
    float* out      = (float*)d_out;
    dim3 grid(NPT, NC);
    GenLayer_57191784514055_kernel<<<grid, dim3(256), 0, stream>>>(x, W, b, out);
}